// Round 2
// baseline (1250.827 us; speedup 1.0000x reference)
//
#include <hip/hip_runtime.h>
#include <hip/hip_bf16.h>

// Spatial RNN, 4 directions, R=8, C=64.
// One block per (direction, line). Reversed directions use negative strides so
// the local recurrence is always t[p] = relu(t[p-1] @ W), t[-1] = 0.
//
// Round 2: single LDS t-buffer (27.8 KB) + register-staged t_new (2 barriers
// per step) instead of ping-pong (55.8 KB, 1 barrier). Raises blocks/CU 2->4.
// Epilogue drains output in 3 rounds of 64 pixels through a 17 KB LDS overlay.

#define HD 192
#define CH 64
#define RSTEPS 8
#define TSTRIDE 72    // shorts per pixel slot (144 B = 36 banks == 4 mod 32 -> 2-way, free)
#define SLOTS 193     // pixel slots incl. zero slot 0 (= t[-1])
#define STG_STRIDE 68 // floats per pixel in fp32 staging overlay (272 B, 16B-aligned)

typedef __attribute__((ext_vector_type(8))) short short8v;
typedef __attribute__((ext_vector_type(4))) float float4v;

static __device__ __forceinline__ short f2bf_rne(float f) {
    unsigned u = __float_as_uint(f);
    u += 0x7FFFu + ((u >> 16) & 1u);
    return (short)(u >> 16);
}

__global__ __launch_bounds__(256, 4) void spatial_rnn_kernel(
    const float* __restrict__ x,
    const float* __restrict__ Wl,
    const float* __restrict__ Wr,
    const float* __restrict__ Wu,
    const float* __restrict__ Wd,
    float* __restrict__ out)
{
    __shared__ __align__(16) short smem_s[SLOTS * TSTRIDE]; // 27,792 B
    float* stg = (float*)smem_s; // epilogue overlay: 64*68*4 = 17,408 B <= 27,792

    const int tid  = threadIdx.x;
    const int dir  = blockIdx.y;
    const int line = blockIdx.x;
    const int b    = line / HD;
    const int rc   = line - b * HD;

    const float* Wp = (dir == 0) ? Wl : (dir == 1) ? Wr : (dir == 2) ? Wu : Wd;

    int xbase, xstride, obase, ostride;
    if (dir == 0) {        // left: forward along w
        xbase   = (b * HD + rc) * HD * CH;
        xstride = CH;
        obase   = (b * HD + rc) * HD * 256;
        ostride = 256;
    } else if (dir == 1) { // right: reversed along w
        xbase   = ((b * HD + rc) * HD + (HD - 1)) * CH;
        xstride = -CH;
        obase   = ((b * HD + rc) * HD + (HD - 1)) * 256 + 64;
        ostride = -256;
    } else if (dir == 2) { // up: forward along h
        xbase   = b * HD * HD * CH + rc * CH;
        xstride = HD * CH;
        obase   = b * HD * HD * 256 + rc * 256 + 128;
        ostride = HD * 256;
    } else {               // down: reversed along h
        xbase   = ((b * HD + (HD - 1)) * HD + rc) * CH;
        xstride = -HD * CH;
        obase   = ((b * HD + (HD - 1)) * HD + rc) * 256 + 192;
        ostride = -HD * 256;
    }

    // ---- load x line -> t buffer (bf16), zero slot 0 ----
    for (int q = tid; q < HD * 16; q += 256) {
        int p  = q >> 4;
        int c4 = (q & 15) << 2;
        const float4 v = *(const float4*)(x + xbase + p * xstride + c4);
        short4 s;
        s.x = f2bf_rne(v.x); s.y = f2bf_rne(v.y);
        s.z = f2bf_rne(v.z); s.w = f2bf_rne(v.w);
        *(short4*)(smem_s + (p + 1) * TSTRIDE + c4) = s;
    }
    if (tid < TSTRIDE) smem_s[tid] = 0;

    // ---- W fragments (A operand): A[d][c] = W[c][d] ----
    const int lane = tid & 63;
    const int wv   = tid >> 6;
    const int q4   = lane >> 4;
    const int l16  = lane & 15;

    short8v Af[2][4];
    #pragma unroll
    for (int kc = 0; kc < 2; ++kc)
        #pragma unroll
        for (int dt = 0; dt < 4; ++dt)
            #pragma unroll
            for (int j = 0; j < 8; ++j)
                Af[kc][dt][j] = f2bf_rne(Wp[(kc * 32 + q4 * 8 + j) * CH + dt * 16 + l16]);

    float4v acc[3][4];
    #pragma unroll
    for (int i = 0; i < 3; ++i)
        #pragma unroll
        for (int dt = 0; dt < 4; ++dt)
            acc[i][dt] = (float4v){0.f, 0.f, 0.f, 0.f};

    // precomputed LDS byte offsets (loop-invariant)
    int rdbase[3], wrbase[3];
    #pragma unroll
    for (int i = 0; i < 3; ++i) {
        const int slot = (wv + i * 4) * 16 + l16; // slot p holds t_prev[p-1]
        rdbase[i] = (slot * TSTRIDE + q4 * 8) * 2;
        wrbase[i] = ((slot + 1) * TSTRIDE + q4 * 4) * 2;
    }

    __syncthreads();

    // ---- 8 recurrent steps, single buffer + register staging ----
    uint2 tnew[3][4];
    for (int k = 0; k < RSTEPS; ++k) {
        #pragma unroll
        for (int i = 0; i < 3; ++i) {
            const short8v B0 = *(const short8v*)((const char*)smem_s + rdbase[i]);
            const short8v B1 = *(const short8v*)((const char*)smem_s + rdbase[i] + 64);
            #pragma unroll
            for (int dt = 0; dt < 4; ++dt) {
                float4v d = {0.f, 0.f, 0.f, 0.f};
                d = __builtin_amdgcn_mfma_f32_16x16x32_bf16(Af[0][dt], B0, d, 0, 0, 0);
                d = __builtin_amdgcn_mfma_f32_16x16x32_bf16(Af[1][dt], B1, d, 0, 0, 0);
                const float v0 = fmaxf(d[0], 0.f);
                const float v1 = fmaxf(d[1], 0.f);
                const float v2 = fmaxf(d[2], 0.f);
                const float v3 = fmaxf(d[3], 0.f);
                acc[i][dt][0] += v0; acc[i][dt][1] += v1;
                acc[i][dt][2] += v2; acc[i][dt][3] += v3;
                if (k < RSTEPS - 1) {
                    __hip_bfloat162 h01 = __float22bfloat162_rn(make_float2(v0, v1));
                    __hip_bfloat162 h23 = __float22bfloat162_rn(make_float2(v2, v3));
                    uint2 wpk;
                    __builtin_memcpy(&wpk.x, &h01, 4);
                    __builtin_memcpy(&wpk.y, &h23, 4);
                    tnew[i][dt] = wpk;
                }
            }
        }
        if (k == RSTEPS - 1) break;
        __syncthreads(); // all reads of t_old complete
        #pragma unroll
        for (int i = 0; i < 3; ++i)
            #pragma unroll
            for (int dt = 0; dt < 4; ++dt)
                *(uint2*)((char*)smem_s + wrbase[i] + dt * 32) = tnew[i][dt];
        __syncthreads(); // all writes of t_new visible
    }

    // ---- epilogue: 3 rounds of 64 pixels through fp32 LDS overlay ----
    #pragma unroll
    for (int i = 0; i < 3; ++i) {
        __syncthreads(); // overlay region free (no more t reads)
        #pragma unroll
        for (int dt = 0; dt < 4; ++dt)
            *(float4v*)(stg + (wv * 16 + l16) * STG_STRIDE + dt * 16 + q4 * 4) = acc[i][dt];
        __syncthreads();
        #pragma unroll
        for (int r = 0; r < 4; ++r) {
            const int q  = tid + r * 256;
            const int pl = q >> 4;
            const int c4 = (q & 15) << 2;
            const int p  = i * 64 + pl;
            const float4  xv = *(const float4*)(x + xbase + p * xstride + c4);
            const float4v sv = *(const float4v*)(stg + pl * STG_STRIDE + c4);
            float4 o;
            o.x = xv.x + sv[0]; o.y = xv.y + sv[1];
            o.z = xv.z + sv[2]; o.w = xv.w + sv[3];
            *(float4*)(out + obase + p * ostride + c4) = o;
        }
    }
}

extern "C" void kernel_launch(void* const* d_in, const int* in_sizes, int n_in,
                              void* d_out, int out_size, void* d_ws, size_t ws_size,
                              hipStream_t stream) {
    const float* x  = (const float*)d_in[0];
    const float* Wl = (const float*)d_in[1];
    const float* Wr = (const float*)d_in[2];
    const float* Wu = (const float*)d_in[3];
    const float* Wd = (const float*)d_in[4];
    float* outp = (float*)d_out;
    dim3 grid(8 * HD, 4);
    spatial_rnn_kernel<<<grid, 256, 0, stream>>>(x, Wl, Wr, Wu, Wd, outp);
}